// Round 2
// baseline (492.518 us; speedup 1.0000x reference)
//
#include <hip/hip_runtime.h>

#define NB 8
#define ND 32
#define NHW (512*512)
#define NK 16
#define IGN 255

// per-image stats workspace layout (floats)
#define WS_S   1088
#define O_CNT  0      // counts[16]
#define O_VPIX 16     // # of valid (mask & !=IGN) pixels
#define O_SUM  32     // sums[16*32]
#define O_CEN  544    // centers[16*32]
#define O_PULL 1056   // pull partial sums[16]
#define O_PUSH 1072
#define O_REG  1073
#define O_VB   1074
#define O_NID  1075

#define IDP_OFF 65536          // byte offset of packed-id region in ws

#define TPB 256
#define CHUNKS 128
#define PIXPB (NHW / CHUNKS)   // 2048 pixels per block
#define ITERS (PIXPB / (TPB * 4))   // 2

__global__ __launch_bounds__(256) void k_zero(float* __restrict__ ws) {
    int i = blockIdx.x * blockDim.x + threadIdx.x;
    if (i < NB * WS_S) ws[i] = 0.f;
}

__global__ __launch_bounds__(TPB, 4) void k_accum(const float* __restrict__ pred,
                                                  const int* __restrict__ inst,
                                                  const unsigned char* __restrict__ msk,
                                                  float* __restrict__ ws,
                                                  unsigned char* __restrict__ idp) {
    __shared__ float ls[2][17][33];   // [half-wave copy][id (16=invalid)][d], banks of copy1 offset by 17
    __shared__ float lcnt[2][17];
    const int tid = threadIdx.x;
    const int b = blockIdx.y, chunk = blockIdx.x;
    const int half = (tid >> 5) & 1;

    for (int i = tid; i < 2 * 17 * 33; i += TPB) ((float*)ls)[i] = 0.f;
    if (tid < 2 * 17) ((float*)lcnt)[tid] = 0.f;
    __syncthreads();

    const size_t img = (size_t)b * NHW;
    const float* pb = pred + (size_t)b * ND * NHW;
    float vcnt = 0.f;

    for (int it = 0; it < ITERS; ++it) {
        const int pix = chunk * PIXPB + it * (TPB * 4) + 4 * tid;
        const int4 id4 = *(const int4*)(inst + img + pix);
        const unsigned m4 = *(const unsigned*)(msk + img + pix);
        const int ida[4] = {id4.x, id4.y, id4.z, id4.w};
        int id[4];
        unsigned pk = 0;
        #pragma unroll
        for (int p = 0; p < 4; ++p) {
            const bool valid = (((m4 >> (8 * p)) & 0xff) != 0) && (ida[p] != IGN);
            vcnt += valid ? 1.f : 0.f;
            id[p] = (valid && (unsigned)ida[p] < NK) ? ida[p] : NK;
            pk |= ((unsigned)id[p]) << (8 * p);
        }
        *(unsigned*)(idp + img + pix) = pk;
        #pragma unroll
        for (int p = 0; p < 4; ++p) atomicAdd(&lcnt[half][id[p]], 1.f);

        #pragma unroll 8
        for (int d = 0; d < ND; ++d) {
            const float4 v = *(const float4*)(pb + (size_t)d * NHW + pix);
            atomicAdd(&ls[half][id[0]][d], v.x);
            atomicAdd(&ls[half][id[1]][d], v.y);
            atomicAdd(&ls[half][id[2]][d], v.z);
            atomicAdd(&ls[half][id[3]][d], v.w);
        }
    }
    __syncthreads();

    float* wb = ws + b * WS_S;
    for (int i = tid; i < NK * ND; i += TPB) {
        const int k = i >> 5, d = i & 31;
        atomicAdd(&wb[O_SUM + i], ls[0][k][d] + ls[1][k][d]);
    }
    if (tid < NK) atomicAdd(&wb[O_CNT + tid], lcnt[0][tid] + lcnt[1][tid]);
    #pragma unroll
    for (int off = 32; off > 0; off >>= 1) vcnt += __shfl_down(vcnt, off);
    if ((tid & 63) == 0) atomicAdd(&wb[O_VPIX], vcnt);
}

__global__ __launch_bounds__(256) void k_centers(float* __restrict__ ws) {
    __shared__ float lc[NK][ND + 1];
    __shared__ float lcnt[NK];
    __shared__ float rsum[256], rcnt[256];
    const int tid = threadIdx.x;
    float* wb = ws + blockIdx.x * WS_S;

    if (tid < NK) lcnt[tid] = wb[O_CNT + tid];
    __syncthreads();
    for (int i = tid; i < NK * ND; i += 256) {
        int k = i >> 5, d = i & 31;
        float c = wb[O_SUM + i] / fmaxf(lcnt[k], 1.f);
        lc[k][d] = c;
        wb[O_CEN + i] = c;
    }
    __syncthreads();

    const int i = tid >> 4, j = tid & 15;
    const bool pm = (i != j) && (lcnt[i] > 0.f) && (lcnt[j] > 0.f);
    float sq = 0.f;
    #pragma unroll
    for (int d = 0; d < ND; ++d) { float df = lc[i][d] - lc[j][d]; sq += df * df; }
    float dm = sqrtf(pm ? sq : 1.f);
    float r = fmaxf(2.f * 1.5f - dm, 0.f);
    rsum[tid] = pm ? r * r : 0.f;
    rcnt[tid] = pm ? 1.f : 0.f;
    __syncthreads();
    for (int s = 128; s > 0; s >>= 1) {
        if (tid < s) { rsum[tid] += rsum[tid + s]; rcnt[tid] += rcnt[tid + s]; }
        __syncthreads();
    }

    if (tid == 0) {
        float nids = 0.f;
        for (int k = 0; k < NK; ++k) nids += (lcnt[k] > 0.f) ? 1.f : 0.f;
        float push = (nids > 1.f) ? rsum[0] / fmaxf(rcnt[0], 1.f) : 0.f;
        float reg = 0.f;
        for (int k = 0; k < NK; ++k) {
            if (lcnt[k] > 0.f) {
                float cs = 0.f;
                for (int d = 0; d < ND; ++d) cs += lc[k][d] * lc[k][d];
                reg += sqrtf(cs);
            }
        }
        reg /= fmaxf(nids, 1.f);
        wb[O_PUSH] = push;
        wb[O_REG] = reg;
        wb[O_VB] = (wb[O_VPIX] > 0.f) ? 1.f : 0.f;
        wb[O_NID] = nids;
    }
}

__global__ __launch_bounds__(TPB, 4) void k_pull(const float* __restrict__ pred,
                                                 const unsigned char* __restrict__ idp,
                                                 float* __restrict__ ws) {
    __shared__ float lc[17][ND + 1];   // row 16 = zeros (invalid)
    __shared__ float lp[2][NK];
    const int tid = threadIdx.x;
    // reversed global order vs k_accum: tail of pass-1 stream is L3-resident
    const int b = NB - 1 - blockIdx.y;
    const int chunk = CHUNKS - 1 - blockIdx.x;
    const int half = (tid >> 5) & 1;
    float* wb = ws + b * WS_S;

    for (int i = tid; i < 17 * ND; i += TPB)
        lc[i >> 5][i & 31] = (i < NK * ND) ? wb[O_CEN + i] : 0.f;
    if (tid < 2 * NK) ((float*)lp)[tid] = 0.f;
    __syncthreads();

    const size_t img = (size_t)b * NHW;
    const float* pb = pred + (size_t)b * ND * NHW;

    for (int it = ITERS - 1; it >= 0; --it) {
        const int pix = chunk * PIXPB + it * (TPB * 4) + 4 * tid;
        const unsigned pk = *(const unsigned*)(idp + img + pix);
        const int id[4] = {(int)(pk & 0xff), (int)((pk >> 8) & 0xff),
                           (int)((pk >> 16) & 0xff), (int)(pk >> 24)};
        float sq[4] = {0.f, 0.f, 0.f, 0.f};
        #pragma unroll 8
        for (int d = 0; d < ND; ++d) {
            const float4 v = *(const float4*)(pb + (size_t)d * NHW + pix);
            float df0 = v.x - lc[id[0]][d];
            float df1 = v.y - lc[id[1]][d];
            float df2 = v.z - lc[id[2]][d];
            float df3 = v.w - lc[id[3]][d];
            sq[0] += df0 * df0; sq[1] += df1 * df1;
            sq[2] += df2 * df2; sq[3] += df3 * df3;
        }
        #pragma unroll
        for (int p = 0; p < 4; ++p) {
            if (id[p] < NK) {
                float r = fmaxf(sqrtf(sq[p]) - 0.5f, 0.f);
                atomicAdd(&lp[half][id[p]], r * r);
            }
        }
    }
    __syncthreads();
    if (tid < NK) atomicAdd(&wb[O_PULL + tid], lp[0][tid] + lp[1][tid]);
}

__global__ void k_final(const float* __restrict__ ws, float* __restrict__ out) {
    const int tid = threadIdx.x;
    float contrib = 0.f, vb = 0.f;
    if (tid < NB) {
        const float* wb = ws + tid * WS_S;
        float nids = wb[O_NID];
        float pull = 0.f;
        for (int k = 0; k < NK; ++k) {
            float c = wb[O_CNT + k];
            if (c > 0.f) pull += wb[O_PULL + k] / fmaxf(c, 1.f);
        }
        pull /= fmaxf(nids, 1.f);
        vb = wb[O_VB];
        contrib = (pull + wb[O_PUSH] + 0.001f * wb[O_REG]) * vb;
    }
    #pragma unroll
    for (int off = 32; off > 0; off >>= 1) {
        contrib += __shfl_down(contrib, off);
        vb += __shfl_down(vb, off);
    }
    if (tid == 0) out[0] = (vb > 0.f) ? contrib / fmaxf(vb, 1.f) : 0.f;
}

extern "C" void kernel_launch(void* const* d_in, const int* in_sizes, int n_in,
                              void* d_out, int out_size, void* d_ws, size_t ws_size,
                              hipStream_t stream) {
    const float* pred = (const float*)d_in[0];
    const int* inst = (const int*)d_in[1];
    const unsigned char* msk = (const unsigned char*)d_in[2];
    float* out = (float*)d_out;
    float* ws = (float*)d_ws;
    unsigned char* idp = (unsigned char*)d_ws + IDP_OFF;

    k_zero<<<(NB * WS_S + 255) / 256, 256, 0, stream>>>(ws);
    dim3 grid(CHUNKS, NB);
    k_accum<<<grid, TPB, 0, stream>>>(pred, inst, msk, ws, idp);
    k_centers<<<NB, 256, 0, stream>>>(ws);
    k_pull<<<grid, TPB, 0, stream>>>(pred, idp, ws);
    k_final<<<1, 64, 0, stream>>>(ws, out);
}

// Round 3
// 183.855 us; speedup vs baseline: 2.6788x; 2.6788x over previous
//
#include <hip/hip_runtime.h>

#define NB 8
#define ND 32
#define NHW (512*512)
#define NK 16
#define IGN 255

// per-image stats workspace layout (floats)
#define WS_S   1088
#define O_CNT  0      // counts[16]
#define O_VPIX 16     // # of valid (mask & !=IGN) pixels
#define O_SUM  32     // sums[16*32]
#define O_CEN  544    // centers[16*32]
#define O_PULL 1056   // pull partial sums[16]
#define O_PUSH 1072
#define O_REG  1073
#define O_VB   1074
#define O_NID  1075

#define IDP_OFF 65536          // byte offset of packed-id region in ws

#define TPB 256
#define CHUNKS 256
#define PIXPB (NHW / CHUNKS)   // 1024
#define ITERS (PIXPB / TPB)    // 4

__global__ __launch_bounds__(256) void k_zero(float* __restrict__ ws) {
    int i = blockIdx.x * blockDim.x + threadIdx.x;
    if (i < NB * WS_S) ws[i] = 0.f;
}

// Pass 1: R1's known-good shape (scalar loads, atomics NOT interleaved with
// vector loads) + 8-way privatized LDS accumulators + fused id-packing.
__global__ __launch_bounds__(TPB) void k_accum(const float* __restrict__ pred,
                                               const int* __restrict__ inst,
                                               const unsigned char* __restrict__ msk,
                                               float* __restrict__ ws,
                                               unsigned char* __restrict__ idp) {
    __shared__ float ls[8][17][33];   // copy = lane&7; ~1.06-way same-addr, ~2-way bank
    __shared__ float lcnt[8][17];
    const int tid = threadIdx.x;
    const int b = blockIdx.y, chunk = blockIdx.x;
    const int c = tid & 7;

    for (int i = tid; i < 8 * 17 * 33; i += TPB) ((float*)ls)[i] = 0.f;
    for (int i = tid; i < 8 * 17; i += TPB) ((float*)lcnt)[i] = 0.f;
    __syncthreads();

    const size_t img = (size_t)b * NHW;
    const float* pb = pred + (size_t)b * ND * NHW;
    float vcnt = 0.f;

    for (int it = 0; it < ITERS; ++it) {
        const int pix = chunk * PIXPB + it * TPB + tid;
        const int id = inst[img + pix];
        const bool m = (msk[img + pix] != 0) && (id != IGN);
        vcnt += m ? 1.f : 0.f;
        const int sid = (m && (unsigned)id < NK) ? id : NK;
        idp[img + pix] = (unsigned char)sid;
        if (sid < NK) {
            atomicAdd(&lcnt[c][sid], 1.f);
            #pragma unroll
            for (int d = 0; d < ND; ++d) {
                float v = pb[(size_t)d * NHW + pix];
                atomicAdd(&ls[c][sid][d], v);
            }
        }
    }
    __syncthreads();

    float* wb = ws + b * WS_S;
    for (int i = tid; i < NK * ND; i += TPB) {
        const int k = i >> 5, d = i & 31;
        float s = 0.f;
        #pragma unroll
        for (int cc = 0; cc < 8; ++cc) s += ls[cc][k][d];
        atomicAdd(&wb[O_SUM + i], s);
    }
    if (tid < NK) {
        float s = 0.f;
        #pragma unroll
        for (int cc = 0; cc < 8; ++cc) s += lcnt[cc][tid];
        atomicAdd(&wb[O_CNT + tid], s);
    }
    #pragma unroll
    for (int off = 32; off > 0; off >>= 1) vcnt += __shfl_down(vcnt, off);
    if ((tid & 63) == 0) atomicAdd(&wb[O_VPIX], vcnt);
}

__global__ __launch_bounds__(256) void k_centers(float* __restrict__ ws) {
    __shared__ float lc[NK][ND + 1];
    __shared__ float lcnt[NK];
    __shared__ float rsum[256], rcnt[256];
    const int tid = threadIdx.x;
    float* wb = ws + blockIdx.x * WS_S;

    if (tid < NK) lcnt[tid] = wb[O_CNT + tid];
    __syncthreads();
    for (int i = tid; i < NK * ND; i += 256) {
        int k = i >> 5, d = i & 31;
        float c = wb[O_SUM + i] / fmaxf(lcnt[k], 1.f);
        lc[k][d] = c;
        wb[O_CEN + i] = c;
    }
    __syncthreads();

    const int i = tid >> 4, j = tid & 15;
    const bool pm = (i != j) && (lcnt[i] > 0.f) && (lcnt[j] > 0.f);
    float sq = 0.f;
    #pragma unroll
    for (int d = 0; d < ND; ++d) { float df = lc[i][d] - lc[j][d]; sq += df * df; }
    float dm = sqrtf(pm ? sq : 1.f);
    float r = fmaxf(2.f * 1.5f - dm, 0.f);
    rsum[tid] = pm ? r * r : 0.f;
    rcnt[tid] = pm ? 1.f : 0.f;
    __syncthreads();
    for (int s = 128; s > 0; s >>= 1) {
        if (tid < s) { rsum[tid] += rsum[tid + s]; rcnt[tid] += rcnt[tid + s]; }
        __syncthreads();
    }

    if (tid == 0) {
        float nids = 0.f;
        for (int k = 0; k < NK; ++k) nids += (lcnt[k] > 0.f) ? 1.f : 0.f;
        float push = (nids > 1.f) ? rsum[0] / fmaxf(rcnt[0], 1.f) : 0.f;
        float reg = 0.f;
        for (int k = 0; k < NK; ++k) {
            if (lcnt[k] > 0.f) {
                float cs = 0.f;
                for (int d = 0; d < ND; ++d) cs += lc[k][d] * lc[k][d];
                reg += sqrtf(cs);
            }
        }
        reg /= fmaxf(nids, 1.f);
        wb[O_PUSH] = push;
        wb[O_REG] = reg;
        wb[O_VB] = (wb[O_VPIX] > 0.f) ? 1.f : 0.f;
        wb[O_NID] = nids;
    }
}

// Pass 2: R2's measured-fast shape (float4, packed ids), 1 iteration/thread.
__global__ __launch_bounds__(TPB) void k_pull(const float* __restrict__ pred,
                                              const unsigned char* __restrict__ idp,
                                              float* __restrict__ ws) {
    __shared__ float lc[17][ND + 1];   // row 16 = zeros (invalid)
    __shared__ float lp[2][NK];
    const int tid = threadIdx.x;
    // reversed global order vs k_accum: tail of pass-1 stream is L3-resident
    const int b = NB - 1 - blockIdx.y;
    const int chunk = CHUNKS - 1 - blockIdx.x;
    const int half = (tid >> 5) & 1;
    float* wb = ws + b * WS_S;

    for (int i = tid; i < 17 * ND; i += TPB)
        lc[i >> 5][i & 31] = (i < NK * ND) ? wb[O_CEN + i] : 0.f;
    if (tid < 2 * NK) ((float*)lp)[tid] = 0.f;
    __syncthreads();

    const size_t img = (size_t)b * NHW;
    const float* pb = pred + (size_t)b * ND * NHW;

    const int pix = chunk * PIXPB + 4 * tid;
    const unsigned pk = *(const unsigned*)(idp + img + pix);
    const int id[4] = {(int)(pk & 0xff), (int)((pk >> 8) & 0xff),
                       (int)((pk >> 16) & 0xff), (int)(pk >> 24)};
    float sq[4] = {0.f, 0.f, 0.f, 0.f};
    #pragma unroll 8
    for (int d = 0; d < ND; ++d) {
        const float4 v = *(const float4*)(pb + (size_t)d * NHW + pix);
        float df0 = v.x - lc[id[0]][d];
        float df1 = v.y - lc[id[1]][d];
        float df2 = v.z - lc[id[2]][d];
        float df3 = v.w - lc[id[3]][d];
        sq[0] += df0 * df0; sq[1] += df1 * df1;
        sq[2] += df2 * df2; sq[3] += df3 * df3;
    }
    #pragma unroll
    for (int p = 0; p < 4; ++p) {
        if (id[p] < NK) {
            float r = fmaxf(sqrtf(sq[p]) - 0.5f, 0.f);
            atomicAdd(&lp[half][id[p]], r * r);
        }
    }
    __syncthreads();
    if (tid < NK) atomicAdd(&wb[O_PULL + tid], lp[0][tid] + lp[1][tid]);
}

__global__ void k_final(const float* __restrict__ ws, float* __restrict__ out) {
    const int tid = threadIdx.x;
    float contrib = 0.f, vb = 0.f;
    if (tid < NB) {
        const float* wb = ws + tid * WS_S;
        float nids = wb[O_NID];
        float pull = 0.f;
        for (int k = 0; k < NK; ++k) {
            float c = wb[O_CNT + k];
            if (c > 0.f) pull += wb[O_PULL + k] / fmaxf(c, 1.f);
        }
        pull /= fmaxf(nids, 1.f);
        vb = wb[O_VB];
        contrib = (pull + wb[O_PUSH] + 0.001f * wb[O_REG]) * vb;
    }
    #pragma unroll
    for (int off = 32; off > 0; off >>= 1) {
        contrib += __shfl_down(contrib, off);
        vb += __shfl_down(vb, off);
    }
    if (tid == 0) out[0] = (vb > 0.f) ? contrib / fmaxf(vb, 1.f) : 0.f;
}

extern "C" void kernel_launch(void* const* d_in, const int* in_sizes, int n_in,
                              void* d_out, int out_size, void* d_ws, size_t ws_size,
                              hipStream_t stream) {
    const float* pred = (const float*)d_in[0];
    const int* inst = (const int*)d_in[1];
    const unsigned char* msk = (const unsigned char*)d_in[2];
    float* out = (float*)d_out;
    float* ws = (float*)d_ws;
    unsigned char* idp = (unsigned char*)d_ws + IDP_OFF;

    k_zero<<<(NB * WS_S + 255) / 256, 256, 0, stream>>>(ws);
    dim3 grid(CHUNKS, NB);
    k_accum<<<grid, TPB, 0, stream>>>(pred, inst, msk, ws, idp);
    k_centers<<<NB, 256, 0, stream>>>(ws);
    k_pull<<<grid, TPB, 0, stream>>>(pred, idp, ws);
    k_final<<<1, 64, 0, stream>>>(ws, out);
}